// Round 1
// baseline (1125.521 us; speedup 1.0000x reference)
//
#include <hip/hip_runtime.h>

// ---------- types / helpers ----------
typedef __attribute__((ext_vector_type(8))) short short8;
typedef __attribute__((ext_vector_type(4))) float f32x4;

__device__ __forceinline__ short f2bf(float f) {
    unsigned u = __builtin_bit_cast(unsigned, f);
    u = (u + 0x7FFFu + ((u >> 16) & 1u)) >> 16;
    return (short)u;
}
__device__ __forceinline__ float bf2f(short h) {
    unsigned u = ((unsigned)(unsigned short)h) << 16;
    return __builtin_bit_cast(float, u);
}

#define NPX 524288L   // 8*256*256
#define CH 64
#define HID 128
#define CH2 256

// ws layout (bytes)
#define OFF_W1T 0L                      // 256*64*2  = 32768
#define OFF_W2T 32768L                  // 64*128*2  = 16384
#define OFF_W3T 49152L                  // 256*64*2  = 32768
#define OFF_W4T 81920L                  // 64*128*2  = 16384
#define OFF_WATT 98304L                 // 8*128*4   = 4096
#define OFF_GPART 102400L               // 8192*128*4 = 4194304
#define OFF_U 4296704L                  // 524288*256*2 = 268435456
#define OFF_X1 4296704L                 // aliases dead u: 524288*64*4 = 134217728
#define OFF_XN2 138514432L              // 524288*64*2 = 67108864 (still inside u)
#define OFF_T 272732160L                // 524288*128*2 = 134217728  -> end ~407MB

// ---------- K0: weight transpose + bf16 cast ----------
__global__ __launch_bounds__(256) void k_prep(
    const float* __restrict__ w1, const float* __restrict__ w2,
    const float* __restrict__ w3, const float* __restrict__ w4,
    short* __restrict__ w1t, short* __restrict__ w2t,
    short* __restrict__ w3t, short* __restrict__ w4t)
{
    int id = blockIdx.x * 256 + threadIdx.x;
    if (id < 64 * 256) {  // w1,w3: [64][256] -> [256][64]
        int ci = id >> 8, co = id & 255;
        w1t[co * 64 + ci] = f2bf(w1[id]);
        w3t[co * 64 + ci] = f2bf(w3[id]);
    }
    if (id < 128 * 64) {  // w2,w4: [128][64] -> [64][128]
        int ci = id >> 6, co = id & 63;
        w2t[co * 128 + ci] = f2bf(w2[id]);
        w4t[co * 128 + ci] = f2bf(w4[id]);
    }
}

// ---------- K1: LN1 + pw1 (MFMA) -> u bf16 [NPX][256] ----------
__global__ __launch_bounds__(256) void k_s1front(
    const float* __restrict__ x, const float* __restrict__ ln1g, const float* __restrict__ ln1b,
    const short* __restrict__ w1t, const float* __restrict__ b1, short* __restrict__ u)
{
    const int lane = threadIdx.x & 63;
    const int wave = threadIdx.x >> 6;
    const int m = lane & 15;
    const int quad = lane >> 4;
    const long px0 = (long)blockIdx.x * 64 + wave * 16;
    const float* xr = x + (px0 + m) * 64;

    float4 f0 = *(const float4*)(xr + quad * 8);
    float4 f1 = *(const float4*)(xr + quad * 8 + 4);
    float4 f2 = *(const float4*)(xr + 32 + quad * 8);
    float4 f3 = *(const float4*)(xr + 32 + quad * 8 + 4);

    float s  = (f0.x + f0.y + f0.z + f0.w) + (f1.x + f1.y + f1.z + f1.w)
             + (f2.x + f2.y + f2.z + f2.w) + (f3.x + f3.y + f3.z + f3.w);
    float s2 = (f0.x*f0.x + f0.y*f0.y + f0.z*f0.z + f0.w*f0.w)
             + (f1.x*f1.x + f1.y*f1.y + f1.z*f1.z + f1.w*f1.w)
             + (f2.x*f2.x + f2.y*f2.y + f2.z*f2.z + f2.w*f2.w)
             + (f3.x*f3.x + f3.y*f3.y + f3.z*f3.z + f3.w*f3.w);
    s  += __shfl_xor(s, 16);  s  += __shfl_xor(s, 32);
    s2 += __shfl_xor(s2, 16); s2 += __shfl_xor(s2, 32);
    float mean = s * 0.015625f;
    float var  = s2 * 0.015625f - mean * mean;
    float rs   = rsqrtf(var + 1e-6f);

    float4 g0 = *(const float4*)(ln1g + quad * 8);
    float4 g1 = *(const float4*)(ln1g + quad * 8 + 4);
    float4 g2 = *(const float4*)(ln1g + 32 + quad * 8);
    float4 g3 = *(const float4*)(ln1g + 32 + quad * 8 + 4);
    float4 c0 = *(const float4*)(ln1b + quad * 8);
    float4 c1 = *(const float4*)(ln1b + quad * 8 + 4);
    float4 c2 = *(const float4*)(ln1b + 32 + quad * 8);
    float4 c3 = *(const float4*)(ln1b + 32 + quad * 8 + 4);

    short8 a0, a1;
    a0[0] = f2bf((f0.x - mean) * rs * g0.x + c0.x);
    a0[1] = f2bf((f0.y - mean) * rs * g0.y + c0.y);
    a0[2] = f2bf((f0.z - mean) * rs * g0.z + c0.z);
    a0[3] = f2bf((f0.w - mean) * rs * g0.w + c0.w);
    a0[4] = f2bf((f1.x - mean) * rs * g1.x + c1.x);
    a0[5] = f2bf((f1.y - mean) * rs * g1.y + c1.y);
    a0[6] = f2bf((f1.z - mean) * rs * g1.z + c1.z);
    a0[7] = f2bf((f1.w - mean) * rs * g1.w + c1.w);
    a1[0] = f2bf((f2.x - mean) * rs * g2.x + c2.x);
    a1[1] = f2bf((f2.y - mean) * rs * g2.y + c2.y);
    a1[2] = f2bf((f2.z - mean) * rs * g2.z + c2.z);
    a1[3] = f2bf((f2.w - mean) * rs * g2.w + c2.w);
    a1[4] = f2bf((f3.x - mean) * rs * g3.x + c3.x);
    a1[5] = f2bf((f3.y - mean) * rs * g3.y + c3.y);
    a1[6] = f2bf((f3.z - mean) * rs * g3.z + c3.z);
    a1[7] = f2bf((f3.w - mean) * rs * g3.w + c3.w);

    f32x4 acc[16];
#pragma unroll
    for (int nt = 0; nt < 16; ++nt) { f32x4 z = {0.f, 0.f, 0.f, 0.f}; acc[nt] = z; }
#pragma unroll
    for (int nt = 0; nt < 16; ++nt) {
        int co = nt * 16 + m;
        short8 b0 = *(const short8*)(w1t + co * 64 + quad * 8);
        short8 b1f = *(const short8*)(w1t + co * 64 + 32 + quad * 8);
        acc[nt] = __builtin_amdgcn_mfma_f32_16x16x32_bf16(a0, b0, acc[nt], 0, 0, 0);
        acc[nt] = __builtin_amdgcn_mfma_f32_16x16x32_bf16(a1, b1f, acc[nt], 0, 0, 0);
    }
#pragma unroll
    for (int nt = 0; nt < 16; ++nt) {
        int co = nt * 16 + m;
        float bias = b1[co];
#pragma unroll
        for (int r = 0; r < 4; ++r) {
            long prow = px0 + quad * 4 + r;
            u[prow * 256 + co] = f2bf(acc[nt][r] + bias);
        }
    }
}

// ---------- K2: dw3x3 + gate + GAP partials ----------
__global__ __launch_bounds__(256) void k_dwgate(
    const short* __restrict__ u, const float* __restrict__ dww, const float* __restrict__ dwb,
    short* __restrict__ t, float* __restrict__ gpart)
{
    __shared__ short uh[100 * 264];   // 10x10 halo x 256ch, row pad 264 (52.8KB)
    const int blk = blockIdx.x;
    const int b  = blk >> 10;
    const int ty = (blk >> 5) & 31;
    const int tx = blk & 31;
    const int tid = threadIdx.x;

    // cooperative halo load (16 threads per halo pixel, 16ch each)
    const int hsub = tid & 15;
    for (int h = tid >> 4; h < 100; h += 16) {
        int hy = h / 10, hx = h - hy * 10;
        int gy = ty * 8 + hy - 1, gx = tx * 8 + hx - 1;
        short8 v0 = {0,0,0,0,0,0,0,0}, v1 = {0,0,0,0,0,0,0,0};
        if (gy >= 0 && gy < 256 && gx >= 0 && gx < 256) {
            const short* src = u + (((long)(b * 256 + gy) * 256) + gx) * 256 + hsub * 16;
            v0 = *(const short8*)(src);
            v1 = *(const short8*)(src + 8);
        }
        *(short8*)&uh[h * 264 + hsub * 16]     = v0;
        *(short8*)&uh[h * 264 + hsub * 16 + 8] = v1;
    }
    __syncthreads();

    const int l  = tid & 63;
    const int cq = tid >> 6;           // wave -> channel quarter
    const int y  = l >> 3, xx = l & 7;
    const long gpx = ((long)(b * 256 + ty * 8 + y) * 256) + tx * 8 + xx;

    for (int chunk = 0; chunk < 4; ++chunk) {
        const int c = cq * 32 + chunk * 8;   // gate channel base (0..127)
        float acc1[8] = {0,0,0,0,0,0,0,0};
        float acc2[8] = {0,0,0,0,0,0,0,0};
#pragma unroll
        for (int dy = 0; dy < 3; ++dy)
#pragma unroll
        for (int dx = 0; dx < 3; ++dx) {
            int h = (y + dy) * 10 + (xx + dx);
            short8 u1 = *(const short8*)&uh[h * 264 + c];
            short8 u2 = *(const short8*)&uh[h * 264 + 128 + c];
            const float* wp = dww + (dy * 3 + dx) * 256 + c;
            float4 wa = *(const float4*)(wp);
            float4 wb = *(const float4*)(wp + 4);
            float4 va = *(const float4*)(wp + 128);
            float4 vb = *(const float4*)(wp + 132);
            acc1[0] += bf2f(u1[0]) * wa.x;  acc1[1] += bf2f(u1[1]) * wa.y;
            acc1[2] += bf2f(u1[2]) * wa.z;  acc1[3] += bf2f(u1[3]) * wa.w;
            acc1[4] += bf2f(u1[4]) * wb.x;  acc1[5] += bf2f(u1[5]) * wb.y;
            acc1[6] += bf2f(u1[6]) * wb.z;  acc1[7] += bf2f(u1[7]) * wb.w;
            acc2[0] += bf2f(u2[0]) * va.x;  acc2[1] += bf2f(u2[1]) * va.y;
            acc2[2] += bf2f(u2[2]) * va.z;  acc2[3] += bf2f(u2[3]) * va.w;
            acc2[4] += bf2f(u2[4]) * vb.x;  acc2[5] += bf2f(u2[5]) * vb.y;
            acc2[6] += bf2f(u2[6]) * vb.z;  acc2[7] += bf2f(u2[7]) * vb.w;
        }
        const float* db1 = dwb + c;
        const float* db2 = dwb + 128 + c;
        float tv[8];
        short8 st;
#pragma unroll
        for (int i = 0; i < 8; ++i) {
            tv[i] = (acc1[i] + db1[i]) * (acc2[i] + db2[i]);
            st[i] = f2bf(tv[i]);
        }
        *(short8*)(t + gpx * 128 + c) = st;
#pragma unroll
        for (int i = 0; i < 8; ++i) {
            float v = tv[i];
            v += __shfl_xor(v, 1);  v += __shfl_xor(v, 2);  v += __shfl_xor(v, 4);
            v += __shfl_xor(v, 8);  v += __shfl_xor(v, 16); v += __shfl_xor(v, 32);
            if (l == 0) gpart[(long)blk * 128 + c + i] = v;
        }
    }
}

// ---------- K3: GAP reduce + SCA matmul ----------
__global__ __launch_bounds__(1024) void k_sca(
    const float* __restrict__ gpart, const float* __restrict__ scaw,
    const float* __restrict__ scab, float* __restrict__ watt)
{
    __shared__ float gl[8 * 128];
    const int tid = threadIdx.x;
    const int b = tid >> 7, c = tid & 127;
    float s = 0.f;
    const float* gp = gpart + (long)b * 1024 * 128 + c;
    for (int i = 0; i < 1024; ++i) s += gp[i * 128];
    gl[tid] = s * (1.0f / 65536.0f);
    __syncthreads();
    float acc = scab[c];
    const float* g0 = gl + b * 128;
    for (int ci = 0; ci < 128; ++ci) acc += g0[ci] * scaw[ci * 128 + c];
    watt[tid] = acc;
}

// ---------- K4: (t*watt) @ w2 + b2, x1 = x + y*beta, LN2 -> x1,xn2 ----------
__global__ __launch_bounds__(256) void k_s1back(
    const short* __restrict__ t, const float* __restrict__ watt,
    const short* __restrict__ w2t, const float* __restrict__ b2,
    const float* __restrict__ x, const float* __restrict__ beta,
    const float* __restrict__ ln2g, const float* __restrict__ ln2b,
    float* __restrict__ x1, short* __restrict__ xn2)
{
    const int lane = threadIdx.x & 63;
    const int wave = threadIdx.x >> 6;
    const int m = lane & 15, quad = lane >> 4;
    const long px0 = (long)blockIdx.x * 64 + wave * 16;
    const int b = (int)(px0 >> 16);
    const float* wa = watt + b * 128;
    const short* tr = t + (px0 + m) * 128;

    short8 afr[4];
#pragma unroll
    for (int kh = 0; kh < 4; ++kh) {
        short8 tv = *(const short8*)(tr + kh * 32 + quad * 8);
        float4 w0 = *(const float4*)(wa + kh * 32 + quad * 8);
        float4 w1v = *(const float4*)(wa + kh * 32 + quad * 8 + 4);
        short8 af;
        af[0] = f2bf(bf2f(tv[0]) * w0.x);  af[1] = f2bf(bf2f(tv[1]) * w0.y);
        af[2] = f2bf(bf2f(tv[2]) * w0.z);  af[3] = f2bf(bf2f(tv[3]) * w0.w);
        af[4] = f2bf(bf2f(tv[4]) * w1v.x); af[5] = f2bf(bf2f(tv[5]) * w1v.y);
        af[6] = f2bf(bf2f(tv[6]) * w1v.z); af[7] = f2bf(bf2f(tv[7]) * w1v.w);
        afr[kh] = af;
    }
    f32x4 acc[4];
#pragma unroll
    for (int nt = 0; nt < 4; ++nt) { f32x4 z = {0.f,0.f,0.f,0.f}; acc[nt] = z; }
#pragma unroll
    for (int nt = 0; nt < 4; ++nt) {
        int co = nt * 16 + m;
#pragma unroll
        for (int kh = 0; kh < 4; ++kh) {
            short8 bfr = *(const short8*)(w2t + co * 128 + kh * 32 + quad * 8);
            acc[nt] = __builtin_amdgcn_mfma_f32_16x16x32_bf16(afr[kh], bfr, acc[nt], 0, 0, 0);
        }
    }
    float x1v[4][4];
#pragma unroll
    for (int nt = 0; nt < 4; ++nt) {
        int co = nt * 16 + m;
        float bb = b2[co], be = beta[co];
#pragma unroll
        for (int r = 0; r < 4; ++r) {
            long prow = px0 + quad * 4 + r;
            float v = x[prow * 64 + co] + (acc[nt][r] + bb) * be;
            x1v[nt][r] = v;
            x1[prow * 64 + co] = v;
        }
    }
#pragma unroll
    for (int r = 0; r < 4; ++r) {
        float s  = x1v[0][r] + x1v[1][r] + x1v[2][r] + x1v[3][r];
        float s2 = x1v[0][r]*x1v[0][r] + x1v[1][r]*x1v[1][r]
                 + x1v[2][r]*x1v[2][r] + x1v[3][r]*x1v[3][r];
        s  += __shfl_xor(s, 1);  s  += __shfl_xor(s, 2);
        s  += __shfl_xor(s, 4);  s  += __shfl_xor(s, 8);
        s2 += __shfl_xor(s2, 1); s2 += __shfl_xor(s2, 2);
        s2 += __shfl_xor(s2, 4); s2 += __shfl_xor(s2, 8);
        float mean = s * 0.015625f;
        float var  = s2 * 0.015625f - mean * mean;
        float rs   = rsqrtf(var + 1e-6f);
        long prow = px0 + quad * 4 + r;
#pragma unroll
        for (int nt = 0; nt < 4; ++nt) {
            int co = nt * 16 + m;
            float v = (x1v[nt][r] - mean) * rs * ln2g[co] + ln2b[co];
            xn2[prow * 64 + co] = f2bf(v);
        }
    }
}

// ---------- K5: pw3 -> gate -> pw4 -> out ----------
__global__ __launch_bounds__(256) void k_s2(
    const short* __restrict__ xn2, const short* __restrict__ w3t, const float* __restrict__ b3,
    const short* __restrict__ w4t, const float* __restrict__ b4,
    const float* __restrict__ x1, const float* __restrict__ gamma, float* __restrict__ out)
{
    __shared__ short zt[4][16 * 136];   // per-wave gated tile, row pad 136 (17.4KB)
    const int lane = threadIdx.x & 63;
    const int wave = threadIdx.x >> 6;
    const int m = lane & 15, quad = lane >> 4;
    const long px0 = (long)blockIdx.x * 64 + wave * 16;
    const short* ar = xn2 + (px0 + m) * 64;
    short8 a0 = *(const short8*)(ar + quad * 8);
    short8 a1 = *(const short8*)(ar + 32 + quad * 8);

    f32x4 accz[16];
#pragma unroll
    for (int nt = 0; nt < 16; ++nt) { f32x4 z = {0.f,0.f,0.f,0.f}; accz[nt] = z; }
#pragma unroll
    for (int nt = 0; nt < 16; ++nt) {
        int co = nt * 16 + m;
        short8 b0 = *(const short8*)(w3t + co * 64 + quad * 8);
        short8 b1f = *(const short8*)(w3t + co * 64 + 32 + quad * 8);
        accz[nt] = __builtin_amdgcn_mfma_f32_16x16x32_bf16(a0, b0, accz[nt], 0, 0, 0);
        accz[nt] = __builtin_amdgcn_mfma_f32_16x16x32_bf16(a1, b1f, accz[nt], 0, 0, 0);
    }
    // gate: (z1+b3a)*(z2+b3b), write D-layout -> A-layout via LDS
#pragma unroll
    for (int ntp = 0; ntp < 8; ++ntp) {
        int c = ntp * 16 + m;
        float ba = b3[c], bb = b3[128 + c];
#pragma unroll
        for (int r = 0; r < 4; ++r) {
            float gv = (accz[ntp][r] + ba) * (accz[ntp + 8][r] + bb);
            zt[wave][(quad * 4 + r) * 136 + c] = f2bf(gv);
        }
    }
    __syncthreads();
    short8 afr[4];
#pragma unroll
    for (int kh = 0; kh < 4; ++kh)
        afr[kh] = *(const short8*)&zt[wave][m * 136 + kh * 32 + quad * 8];

    f32x4 acc[4];
#pragma unroll
    for (int nt = 0; nt < 4; ++nt) { f32x4 z = {0.f,0.f,0.f,0.f}; acc[nt] = z; }
#pragma unroll
    for (int nt = 0; nt < 4; ++nt) {
        int co = nt * 16 + m;
#pragma unroll
        for (int kh = 0; kh < 4; ++kh) {
            short8 bfr = *(const short8*)(w4t + co * 128 + kh * 32 + quad * 8);
            acc[nt] = __builtin_amdgcn_mfma_f32_16x16x32_bf16(afr[kh], bfr, acc[nt], 0, 0, 0);
        }
    }
#pragma unroll
    for (int nt = 0; nt < 4; ++nt) {
        int co = nt * 16 + m;
        float bb = b4[co], gm = gamma[co];
#pragma unroll
        for (int r = 0; r < 4; ++r) {
            long prow = px0 + quad * 4 + r;
            out[prow * 64 + co] = x1[prow * 64 + co] + (acc[nt][r] + bb) * gm;
        }
    }
}

// ---------- launch ----------
extern "C" void kernel_launch(void* const* d_in, const int* in_sizes, int n_in,
                              void* d_out, int out_size, void* d_ws, size_t ws_size,
                              hipStream_t stream) {
    (void)in_sizes; (void)n_in; (void)out_size; (void)ws_size;
    const float* x    = (const float*)d_in[0];
    const float* ln1g = (const float*)d_in[1];
    const float* ln1b = (const float*)d_in[2];
    const float* pw1w = (const float*)d_in[3];
    const float* pw1b = (const float*)d_in[4];
    const float* dww  = (const float*)d_in[5];
    const float* dwb  = (const float*)d_in[6];
    const float* scaw = (const float*)d_in[7];
    const float* scab = (const float*)d_in[8];
    const float* pw2w = (const float*)d_in[9];
    const float* pw2b = (const float*)d_in[10];
    const float* beta = (const float*)d_in[11];
    const float* ln2g = (const float*)d_in[12];
    const float* ln2b = (const float*)d_in[13];
    const float* pw3w = (const float*)d_in[14];
    const float* pw3b = (const float*)d_in[15];
    const float* pw4w = (const float*)d_in[16];
    const float* pw4b = (const float*)d_in[17];
    const float* gamma= (const float*)d_in[18];

    char* ws = (char*)d_ws;
    short* w1t = (short*)(ws + OFF_W1T);
    short* w2t = (short*)(ws + OFF_W2T);
    short* w3t = (short*)(ws + OFF_W3T);
    short* w4t = (short*)(ws + OFF_W4T);
    float* watt = (float*)(ws + OFF_WATT);
    float* gpart = (float*)(ws + OFF_GPART);
    short* u   = (short*)(ws + OFF_U);
    float* x1  = (float*)(ws + OFF_X1);
    short* xn2 = (short*)(ws + OFF_XN2);
    short* t   = (short*)(ws + OFF_T);
    float* out = (float*)d_out;

    k_prep<<<64, 256, 0, stream>>>(pw1w, pw2w, pw3w, pw4w, w1t, w2t, w3t, w4t);
    k_s1front<<<8192, 256, 0, stream>>>(x, ln1g, ln1b, w1t, pw1b, u);
    k_dwgate<<<8192, 256, 0, stream>>>(u, dww, dwb, t, gpart);
    k_sca<<<1, 1024, 0, stream>>>(gpart, scaw, scab, watt);
    k_s1back<<<8192, 256, 0, stream>>>(t, watt, w2t, pw2b, x, beta, ln2g, ln2b, x1, xn2);
    k_s2<<<8192, 256, 0, stream>>>(xn2, w3t, pw3b, w4t, pw4b, x1, gamma, out);
}

// Round 2
// 931.927 us; speedup vs baseline: 1.2077x; 1.2077x over previous
//
#include <hip/hip_runtime.h>

// ---------- types / helpers ----------
typedef __attribute__((ext_vector_type(8))) short short8;
typedef __attribute__((ext_vector_type(4))) short short4_t;
typedef __attribute__((ext_vector_type(4))) float f32x4;

__device__ __forceinline__ short f2bf(float f) {
    unsigned u = __builtin_bit_cast(unsigned, f);
    u = (u + 0x7FFFu + ((u >> 16) & 1u)) >> 16;
    return (short)u;
}
__device__ __forceinline__ float bf2f(short h) {
    unsigned u = ((unsigned)(unsigned short)h) << 16;
    return __builtin_bit_cast(float, u);
}

// ws layout (bytes)
#define OFF_W1T 0L            // 256*64*2  = 32768
#define OFF_W2T 32768L        // 64*128*2  = 16384
#define OFF_W3T 49152L        // 256*64*2  = 32768
#define OFF_W4T 81920L        // 64*128*2  = 16384
#define OFF_WATT 98304L       // 8*128*4   = 4096
#define OFF_GPART 102400L     // 16384*64*4 = 4194304
#define OFF_GPART2 4296704L   // 64*128*4 = 32768
#define OFF_T 4329472L        // 524288*128*2 = 134217728

// ---------- K0: weight transpose + bf16 cast ----------
__global__ __launch_bounds__(256) void k_prep(
    const float* __restrict__ w1, const float* __restrict__ w2,
    const float* __restrict__ w3, const float* __restrict__ w4,
    short* __restrict__ w1t, short* __restrict__ w2t,
    short* __restrict__ w3t, short* __restrict__ w4t)
{
    int id = blockIdx.x * 256 + threadIdx.x;
    if (id < 64 * 256) {  // w1,w3: [64][256] -> [256][64]
        int ci = id >> 8, co = id & 255;
        w1t[co * 64 + ci] = f2bf(w1[id]);
        w3t[co * 64 + ci] = f2bf(w3[id]);
    }
    if (id < 128 * 64) {  // w2,w4: [128][64] -> [64][128]
        int ci = id >> 6, co = id & 63;
        w2t[co * 128 + ci] = f2bf(w2[id]);
        w4t[co * 128 + ci] = f2bf(w4[id]);
    }
}

// ---------- K_A: fused LN1 + pw1(MFMA) + dw3x3 + gate + GAP partials ----------
// Grid: 16384 = 8 batch x 32 ty x 32 tx x 2 cs (channel-split gate-half).
// Block computes u for a 10x10 halo of its 8x8 tile, 128 of the 256 u
// channels (z1: cs*64..+64, z2: 128+cs*64..+64), entirely in LDS.
#define UST 136   // LDS row stride (shorts): 128 + 8 pad (68 dwords % 32 == 4)
__global__ __launch_bounds__(256) void k_a(
    const float* __restrict__ x, const float* __restrict__ ln1g, const float* __restrict__ ln1b,
    const short* __restrict__ w1t, const float* __restrict__ b1,
    const float* __restrict__ dww, const float* __restrict__ dwb,
    short* __restrict__ t, float* __restrict__ gpart)
{
    __shared__ short uh[100 * UST];   // 27200 B
    const int blk = blockIdx.x;
    const int cs  = blk & 1;
    const int txy = blk >> 1;
    const int tx  = txy & 31;
    const int ty  = (txy >> 5) & 31;
    const int b   = txy >> 10;
    const int tid = threadIdx.x;
    const int lane = tid & 63;
    const int wave = tid >> 6;
    const int m    = lane & 15;
    const int quad = lane >> 4;

    // per-lane LN affine params for ci = quad*8..+8 and 32+quad*8..+8
    f32x4 g0 = *(const f32x4*)(ln1g + quad * 8);
    f32x4 g1 = *(const f32x4*)(ln1g + quad * 8 + 4);
    f32x4 g2 = *(const f32x4*)(ln1g + 32 + quad * 8);
    f32x4 g3 = *(const f32x4*)(ln1g + 32 + quad * 8 + 4);
    f32x4 c0 = *(const f32x4*)(ln1b + quad * 8);
    f32x4 c1 = *(const f32x4*)(ln1b + quad * 8 + 4);
    f32x4 c2 = *(const f32x4*)(ln1b + 32 + quad * 8);
    f32x4 c3 = *(const f32x4*)(ln1b + 32 + quad * 8 + 4);

    // ---- phase 1: u tile via LN1 + pw1 (A = w1 rows, B = ln1(x) cols=pixels)
    for (int tt = wave; tt < 7; tt += 4) {
        int p  = tt * 16 + m;
        int hy = (p * 205) >> 11;          // p/10 for p<112
        int hx = p - hy * 10;
        int gy = ty * 8 + hy - 1, gx = tx * 8 + hx - 1;
        bool pin = (p < 100);
        bool img = pin && gy >= 0 && gy < 256 && gx >= 0 && gx < 256;

        f32x4 f0 = {0,0,0,0}, f1 = {0,0,0,0}, f2 = {0,0,0,0}, f3 = {0,0,0,0};
        if (img) {
            const float* xr = x + ((long)((b * 256 + gy) * 256 + gx)) * 64;
            f0 = *(const f32x4*)(xr + quad * 8);
            f1 = *(const f32x4*)(xr + quad * 8 + 4);
            f2 = *(const f32x4*)(xr + 32 + quad * 8);
            f3 = *(const f32x4*)(xr + 32 + quad * 8 + 4);
        }
        float s  = (f0[0]+f0[1]+f0[2]+f0[3]) + (f1[0]+f1[1]+f1[2]+f1[3])
                 + (f2[0]+f2[1]+f2[2]+f2[3]) + (f3[0]+f3[1]+f3[2]+f3[3]);
        float s2 = (f0[0]*f0[0]+f0[1]*f0[1]+f0[2]*f0[2]+f0[3]*f0[3])
                 + (f1[0]*f1[0]+f1[1]*f1[1]+f1[2]*f1[2]+f1[3]*f1[3])
                 + (f2[0]*f2[0]+f2[1]*f2[1]+f2[2]*f2[2]+f2[3]*f2[3])
                 + (f3[0]*f3[0]+f3[1]*f3[1]+f3[2]*f3[2]+f3[3]*f3[3]);
        s  += __shfl_xor(s, 16);  s  += __shfl_xor(s, 32);
        s2 += __shfl_xor(s2, 16); s2 += __shfl_xor(s2, 32);
        float mean = s * 0.015625f;
        float var  = s2 * 0.015625f - mean * mean;
        float rs   = rsqrtf(var + 1e-6f);

        short8 a0 = {0,0,0,0,0,0,0,0}, a1 = {0,0,0,0,0,0,0,0};
        if (img) {
            a0[0]=f2bf((f0[0]-mean)*rs*g0[0]+c0[0]); a0[1]=f2bf((f0[1]-mean)*rs*g0[1]+c0[1]);
            a0[2]=f2bf((f0[2]-mean)*rs*g0[2]+c0[2]); a0[3]=f2bf((f0[3]-mean)*rs*g0[3]+c0[3]);
            a0[4]=f2bf((f1[0]-mean)*rs*g1[0]+c1[0]); a0[5]=f2bf((f1[1]-mean)*rs*g1[1]+c1[1]);
            a0[6]=f2bf((f1[2]-mean)*rs*g1[2]+c1[2]); a0[7]=f2bf((f1[3]-mean)*rs*g1[3]+c1[3]);
            a1[0]=f2bf((f2[0]-mean)*rs*g2[0]+c2[0]); a1[1]=f2bf((f2[1]-mean)*rs*g2[1]+c2[1]);
            a1[2]=f2bf((f2[2]-mean)*rs*g2[2]+c2[2]); a1[3]=f2bf((f2[3]-mean)*rs*g2[3]+c2[3]);
            a1[4]=f2bf((f3[0]-mean)*rs*g3[0]+c3[0]); a1[5]=f2bf((f3[1]-mean)*rs*g3[1]+c3[1]);
            a1[6]=f2bf((f3[2]-mean)*rs*g3[2]+c3[2]); a1[7]=f2bf((f3[3]-mean)*rs*g3[3]+c3[3]);
        }
#pragma unroll
        for (int cot = 0; cot < 8; ++cot) {
            int cob = (cot < 4) ? (cs * 64 + cot * 16) : (128 + cs * 64 + (cot - 4) * 16);
            short8 wlo = *(const short8*)(w1t + (cob + m) * 64 + quad * 8);
            short8 whi = *(const short8*)(w1t + (cob + m) * 64 + 32 + quad * 8);
            f32x4 acc = {0.f, 0.f, 0.f, 0.f};
            acc = __builtin_amdgcn_mfma_f32_16x16x32_bf16(wlo, a0, acc, 0, 0, 0);
            acc = __builtin_amdgcn_mfma_f32_16x16x32_bf16(whi, a1, acc, 0, 0, 0);
            if (pin) {
                f32x4 bv = *(const f32x4*)(b1 + cob + quad * 4);
                short4_t pk;
#pragma unroll
                for (int r = 0; r < 4; ++r)
                    pk[r] = img ? f2bf(acc[r] + bv[r]) : (short)0;
                *(short4_t*)&uh[p * UST + cot * 16 + quad * 4] = pk;
            }
        }
    }
    __syncthreads();

    // ---- phase 2: dw3x3 + gate + t store + GAP partials
    const int y = lane >> 3, xx = lane & 7;
    const int cq = wave;                         // 16 gate channels per wave
    const int gc0 = cs * 64 + cq * 16;           // global gate channel base
    const long gpx = ((long)(b * 256 + ty * 8 + y) * 256) + tx * 8 + xx;

    float ac1[16], ac2[16];
#pragma unroll
    for (int i = 0; i < 16; ++i) { ac1[i] = 0.f; ac2[i] = 0.f; }
#pragma unroll
    for (int dy = 0; dy < 3; ++dy)
#pragma unroll
    for (int dx = 0; dx < 3; ++dx) {
        int h = (y + dy) * 10 + (xx + dx);
        short8 u1a = *(const short8*)&uh[h * UST + cq * 16];
        short8 u1b = *(const short8*)&uh[h * UST + cq * 16 + 8];
        short8 u2a = *(const short8*)&uh[h * UST + 64 + cq * 16];
        short8 u2b = *(const short8*)&uh[h * UST + 64 + cq * 16 + 8];
        const float* wp = dww + (dy * 3 + dx) * 256 + gc0;
        f32x4 wz0 = *(const f32x4*)(wp);
        f32x4 wz1 = *(const f32x4*)(wp + 4);
        f32x4 wz2 = *(const f32x4*)(wp + 8);
        f32x4 wz3 = *(const f32x4*)(wp + 12);
        f32x4 vz0 = *(const f32x4*)(wp + 128);
        f32x4 vz1 = *(const f32x4*)(wp + 132);
        f32x4 vz2 = *(const f32x4*)(wp + 136);
        f32x4 vz3 = *(const f32x4*)(wp + 140);
#pragma unroll
        for (int i = 0; i < 4; ++i) {
            ac1[i]      += bf2f(u1a[i])     * wz0[i];
            ac1[i + 4]  += bf2f(u1a[i + 4]) * wz1[i];
            ac1[i + 8]  += bf2f(u1b[i])     * wz2[i];
            ac1[i + 12] += bf2f(u1b[i + 4]) * wz3[i];
            ac2[i]      += bf2f(u2a[i])     * vz0[i];
            ac2[i + 4]  += bf2f(u2a[i + 4]) * vz1[i];
            ac2[i + 8]  += bf2f(u2b[i])     * vz2[i];
            ac2[i + 12] += bf2f(u2b[i + 4]) * vz3[i];
        }
    }
    float tv[16];
    short8 st0, st1;
#pragma unroll
    for (int i = 0; i < 16; ++i) {
        float b1v = dwb[gc0 + i];
        float b2v = dwb[128 + gc0 + i];
        tv[i] = (ac1[i] + b1v) * (ac2[i] + b2v);
        if (i < 8) st0[i] = f2bf(tv[i]); else st1[i - 8] = f2bf(tv[i]);
    }
    *(short8*)(t + gpx * 128 + gc0)     = st0;
    *(short8*)(t + gpx * 128 + gc0 + 8) = st1;
#pragma unroll
    for (int i = 0; i < 16; ++i) {
        float v = tv[i];
        v += __shfl_xor(v, 1);  v += __shfl_xor(v, 2);  v += __shfl_xor(v, 4);
        v += __shfl_xor(v, 8);  v += __shfl_xor(v, 16); v += __shfl_xor(v, 32);
        if (lane == 0) gpart[(long)blk * 64 + cq * 16 + i] = v;
    }
}

// ---------- K_R: first-level GAP reduce: gpart[16384][64] -> gpart2[64][128] ----------
__global__ __launch_bounds__(256) void k_red(
    const float* __restrict__ gpart, float* __restrict__ gpart2)
{
    __shared__ float red[256];
    const int b   = blockIdx.x >> 3;
    const int oct = blockIdx.x & 7;
    const int tid = threadIdx.x;
    const int c   = tid & 127;        // global gate channel 0..127
    const int half= tid >> 7;
    const int csl = c >> 6, lc = c & 63;
    float s = 0.f;
    const int i0 = oct * 128 + half * 64;
    for (int i = 0; i < 64; ++i) {
        long idx = ((long)(b * 1024 + i0 + i) * 2 + csl) * 64 + lc;
        s += gpart[idx];
    }
    red[tid] = s;
    __syncthreads();
    if (tid < 128) gpart2[(b * 8 + oct) * 128 + c] = red[c] + red[c + 128];
}

// ---------- K_S: final GAP + SCA matmul -> watt[8][128] ----------
__global__ __launch_bounds__(1024) void k_sca2(
    const float* __restrict__ gpart2, const float* __restrict__ scaw,
    const float* __restrict__ scab, float* __restrict__ watt)
{
    __shared__ float gl[1024];
    const int tid = threadIdx.x;
    const int b = tid >> 7, c = tid & 127;
    float s = 0.f;
#pragma unroll
    for (int oct = 0; oct < 8; ++oct) s += gpart2[(b * 8 + oct) * 128 + c];
    gl[tid] = s * (1.0f / 65536.0f);
    __syncthreads();
    float acc = scab[c];
    const float* g0 = gl + b * 128;
    for (int ci = 0; ci < 128; ++ci) acc += g0[ci] * scaw[ci * 128 + c];
    watt[tid] = acc;
}

// ---------- K_B: fused pw2 + residual + LN2 + pw3 + gate + pw4 + residual ----------
#define XLST 72    // xn2 LDS row stride (shorts)
#define ZTST 136   // z LDS row stride (shorts)
__global__ __launch_bounds__(256) void k_b(
    const short* __restrict__ t, const float* __restrict__ watt,
    const short* __restrict__ w2t, const float* __restrict__ b2,
    const float* __restrict__ x, const float* __restrict__ beta,
    const float* __restrict__ ln2g, const float* __restrict__ ln2b,
    const short* __restrict__ w3t, const float* __restrict__ b3,
    const short* __restrict__ w4t, const float* __restrict__ b4,
    const float* __restrict__ gamma, float* __restrict__ out)
{
    __shared__ short xl[4][16 * XLST];   // 9216 B
    __shared__ short zt[4][16 * ZTST];   // 17408 B
    const int lane = threadIdx.x & 63;
    const int wave = threadIdx.x >> 6;
    const int m = lane & 15, quad = lane >> 4;
    const long px0 = (long)blockIdx.x * 64 + wave * 16;
    const int b = (int)(px0 >> 16);
    const float* wa = watt + b * 128;

    // B-frags: scaled t, B[k=kh*32+quad*8+j][n=px=m]
    const short* tr = t + (px0 + m) * 128;
    short8 bfr[4];
#pragma unroll
    for (int kh = 0; kh < 4; ++kh) {
        short8 tvv = *(const short8*)(tr + kh * 32 + quad * 8);
        f32x4 w0 = *(const f32x4*)(wa + kh * 32 + quad * 8);
        f32x4 w1v = *(const f32x4*)(wa + kh * 32 + quad * 8 + 4);
        short8 af;
        af[0] = f2bf(bf2f(tvv[0]) * w0[0]);  af[1] = f2bf(bf2f(tvv[1]) * w0[1]);
        af[2] = f2bf(bf2f(tvv[2]) * w0[2]);  af[3] = f2bf(bf2f(tvv[3]) * w0[3]);
        af[4] = f2bf(bf2f(tvv[4]) * w1v[0]); af[5] = f2bf(bf2f(tvv[5]) * w1v[1]);
        af[6] = f2bf(bf2f(tvv[6]) * w1v[2]); af[7] = f2bf(bf2f(tvv[7]) * w1v[3]);
        bfr[kh] = af;
    }
    // pw2: A = w2 rows (co), D[row=co][col=px]
    f32x4 acc2[4];
#pragma unroll
    for (int nt = 0; nt < 4; ++nt) { f32x4 z = {0.f,0.f,0.f,0.f}; acc2[nt] = z; }
#pragma unroll
    for (int nt = 0; nt < 4; ++nt)
#pragma unroll
        for (int kh = 0; kh < 4; ++kh) {
            short8 aw = *(const short8*)(w2t + (nt * 16 + m) * 128 + kh * 32 + quad * 8);
            acc2[nt] = __builtin_amdgcn_mfma_f32_16x16x32_bf16(aw, bfr[kh], acc2[nt], 0, 0, 0);
        }
    // x1 = x + (pw2+b2)*beta   (lane holds co=nt*16+quad*4+r, px=m)
    float x1v[4][4];
#pragma unroll
    for (int nt = 0; nt < 4; ++nt) {
        int cob = nt * 16 + quad * 4;
        f32x4 xv = *(const f32x4*)(x + (px0 + m) * 64 + cob);
        f32x4 bb = *(const f32x4*)(b2 + cob);
        f32x4 be = *(const f32x4*)(beta + cob);
#pragma unroll
        for (int r = 0; r < 4; ++r)
            x1v[nt][r] = xv[r] + (acc2[nt][r] + bb[r]) * be[r];
    }
    // LN2 over 64 co: in-lane 16 + shuffle over quads
    float s = 0.f, s2 = 0.f;
#pragma unroll
    for (int nt = 0; nt < 4; ++nt)
#pragma unroll
        for (int r = 0; r < 4; ++r) { s += x1v[nt][r]; s2 += x1v[nt][r] * x1v[nt][r]; }
    s  += __shfl_xor(s, 16);  s  += __shfl_xor(s, 32);
    s2 += __shfl_xor(s2, 16); s2 += __shfl_xor(s2, 32);
    float mean = s * 0.015625f;
    float var  = s2 * 0.015625f - mean * mean;
    float rs   = rsqrtf(var + 1e-6f);
    // xn2 -> LDS (b64-packed per nt)
#pragma unroll
    for (int nt = 0; nt < 4; ++nt) {
        int cob = nt * 16 + quad * 4;
        f32x4 gg = *(const f32x4*)(ln2g + cob);
        f32x4 cc = *(const f32x4*)(ln2b + cob);
        short4_t pk;
#pragma unroll
        for (int r = 0; r < 4; ++r)
            pk[r] = f2bf((x1v[nt][r] - mean) * rs * gg[r] + cc[r]);
        *(short4_t*)&xl[wave][m * XLST + cob] = pk;
    }
    __syncthreads();
    // pw3 (paired tiles for gate): B = xn2 from LDS
    short8 xb0 = *(const short8*)&xl[wave][m * XLST + quad * 8];
    short8 xb1 = *(const short8*)&xl[wave][m * XLST + 32 + quad * 8];
#pragma unroll
    for (int pg = 0; pg < 8; ++pg) {
        f32x4 aA = {0.f,0.f,0.f,0.f}, aB = {0.f,0.f,0.f,0.f};
        short8 w3a0 = *(const short8*)(w3t + (pg * 16 + m) * 64 + quad * 8);
        short8 w3a1 = *(const short8*)(w3t + (pg * 16 + m) * 64 + 32 + quad * 8);
        short8 w3b0 = *(const short8*)(w3t + (128 + pg * 16 + m) * 64 + quad * 8);
        short8 w3b1 = *(const short8*)(w3t + (128 + pg * 16 + m) * 64 + 32 + quad * 8);
        aA = __builtin_amdgcn_mfma_f32_16x16x32_bf16(w3a0, xb0, aA, 0, 0, 0);
        aA = __builtin_amdgcn_mfma_f32_16x16x32_bf16(w3a1, xb1, aA, 0, 0, 0);
        aB = __builtin_amdgcn_mfma_f32_16x16x32_bf16(w3b0, xb0, aB, 0, 0, 0);
        aB = __builtin_amdgcn_mfma_f32_16x16x32_bf16(w3b1, xb1, aB, 0, 0, 0);
        int cb = pg * 16 + quad * 4;
        f32x4 bA = *(const f32x4*)(b3 + cb);
        f32x4 bB = *(const f32x4*)(b3 + 128 + cb);
        short4_t pk;
#pragma unroll
        for (int r = 0; r < 4; ++r)
            pk[r] = f2bf((aA[r] + bA[r]) * (aB[r] + bB[r]));
        *(short4_t*)&zt[wave][m * ZTST + cb] = pk;
    }
    __syncthreads();
    // pw4: B = gated z from LDS
    short8 zb[4];
#pragma unroll
    for (int kh = 0; kh < 4; ++kh)
        zb[kh] = *(const short8*)&zt[wave][m * ZTST + kh * 32 + quad * 8];
    f32x4 acc4[4];
#pragma unroll
    for (int nt = 0; nt < 4; ++nt) { f32x4 z = {0.f,0.f,0.f,0.f}; acc4[nt] = z; }
#pragma unroll
    for (int nt = 0; nt < 4; ++nt)
#pragma unroll
        for (int kh = 0; kh < 4; ++kh) {
            short8 aw = *(const short8*)(w4t + (nt * 16 + m) * 128 + kh * 32 + quad * 8);
            acc4[nt] = __builtin_amdgcn_mfma_f32_16x16x32_bf16(aw, zb[kh], acc4[nt], 0, 0, 0);
        }
    // out = x1 + (pw4+b4)*gamma  (coalesced float4 stores)
#pragma unroll
    for (int nt = 0; nt < 4; ++nt) {
        int cob = nt * 16 + quad * 4;
        f32x4 bb = *(const f32x4*)(b4 + cob);
        f32x4 gm = *(const f32x4*)(gamma + cob);
        f32x4 o;
#pragma unroll
        for (int r = 0; r < 4; ++r)
            o[r] = x1v[nt][r] + (acc4[nt][r] + bb[r]) * gm[r];
        *(f32x4*)(out + (px0 + m) * 64 + cob) = o;
    }
}

// ---------- launch ----------
extern "C" void kernel_launch(void* const* d_in, const int* in_sizes, int n_in,
                              void* d_out, int out_size, void* d_ws, size_t ws_size,
                              hipStream_t stream) {
    (void)in_sizes; (void)n_in; (void)out_size; (void)ws_size;
    const float* x    = (const float*)d_in[0];
    const float* ln1g = (const float*)d_in[1];
    const float* ln1b = (const float*)d_in[2];
    const float* pw1w = (const float*)d_in[3];
    const float* pw1b = (const float*)d_in[4];
    const float* dww  = (const float*)d_in[5];
    const float* dwb  = (const float*)d_in[6];
    const float* scaw = (const float*)d_in[7];
    const float* scab = (const float*)d_in[8];
    const float* pw2w = (const float*)d_in[9];
    const float* pw2b = (const float*)d_in[10];
    const float* beta = (const float*)d_in[11];
    const float* ln2g = (const float*)d_in[12];
    const float* ln2b = (const float*)d_in[13];
    const float* pw3w = (const float*)d_in[14];
    const float* pw3b = (const float*)d_in[15];
    const float* pw4w = (const float*)d_in[16];
    const float* pw4b = (const float*)d_in[17];
    const float* gamma= (const float*)d_in[18];

    char* ws = (char*)d_ws;
    short* w1t = (short*)(ws + OFF_W1T);
    short* w2t = (short*)(ws + OFF_W2T);
    short* w3t = (short*)(ws + OFF_W3T);
    short* w4t = (short*)(ws + OFF_W4T);
    float* watt = (float*)(ws + OFF_WATT);
    float* gpart = (float*)(ws + OFF_GPART);
    float* gpart2 = (float*)(ws + OFF_GPART2);
    short* t   = (short*)(ws + OFF_T);
    float* out = (float*)d_out;

    k_prep<<<64, 256, 0, stream>>>(pw1w, pw2w, pw3w, pw4w, w1t, w2t, w3t, w4t);
    k_a<<<16384, 256, 0, stream>>>(x, ln1g, ln1b, w1t, pw1b, dww, dwb, t, gpart);
    k_red<<<64, 256, 0, stream>>>(gpart, gpart2);
    k_sca2<<<1, 1024, 0, stream>>>(gpart2, scaw, scab, watt);
    k_b<<<8192, 256, 0, stream>>>(t, watt, w2t, pw2b, x, beta, ln2g, ln2b,
                                  w3t, pw3b, w4t, pw4b, gamma, out);
}